// Round 4
// baseline (1050.517 us; speedup 1.0000x reference)
//
#include <hip/hip_runtime.h>

// ======================================================================
// Involution net: 3 x (1x1 conv + dynamic-kernel apply w/ batch BN) + FC
// B=1024.  R4: the three per-image GEMMs use bf16 MFMA (16x16x32),
// fp32 accumulate.  fp32 VALU floor was ~112us for the GEMMs; MFMA
// makes them HBM-bound (~60us combined).
//
// Layouts (HW-verified, learn_hip m89/m91):
//   A-frag: A[m=lane&15][k=(lane>>4)*8+j], k-contiguous (ds_read_b128)
//   B-frag: X^T[n=lane&15][k=...], same k pattern (X transposed in LDS)
//   C/D   : col(n)=lane&15, row(m)=(lane>>4)*4+reg
// LDS row stride 40 bf16 (80B): frag b128 reads hit disjoint 4-bank
// spans, 2 lanes each -> conflict-free.  Weights pre-packed to
// [chunk][M][32] bf16, zero-padded in K -> linear 16B staging, no tail.
// ======================================================================

typedef __attribute__((ext_vector_type(8))) short short8;
typedef __attribute__((ext_vector_type(4))) float floatx4;

// ---------------- workspace layout (float offsets) ----------------
static constexpr size_t OFF_AB1  = 0;         // 7*128*32 ushort = 14336 floats
static constexpr size_t OFF_AB2  = 14336;     // 2*256*32 ushort =  8192 floats
static constexpr size_t OFF_AB3  = 22528;     // 4*512*32 ushort = 32768 floats
static constexpr size_t OFF_SUM1 = 55296;
static constexpr size_t OFF_SQS1 = 55360;
static constexpr size_t OFF_SUM2 = 55424;
static constexpr size_t OFF_SQS2 = 55552;
static constexpr size_t OFF_SUM3 = 55680;
static constexpr size_t OFF_SQS3 = 55936;     // stats end 56192
static constexpr size_t OFF_XI   = 56320;     // 16777216
static constexpr size_t OFF_RPRE = 16833536;  //  4194304
static constexpr size_t OFF_OUT1 = 21027840;  //  4194304
static constexpr size_t OFF_OUT2 = 25222144;  //  2097152
static constexpr size_t OFF_OUT3 = 27319296;  //  4194304 -> 31513600 total

__device__ inline unsigned short f2bf(float f) {
    unsigned u = __float_as_uint(f);
    unsigned r = (u + 0x7FFFu + ((u >> 16) & 1u)) >> 16;
    return (unsigned short)r;
}

// ---------------- prep: pack weights to bf16 K-chunk blocks + zero stats ---
// ab[c][m][kk] = bf16( k=c*32+kk < K ? wcat[m][k] : 0 )
__global__ void prep_all(const float* __restrict__ wi1, const float* __restrict__ wr1,
                         const float* __restrict__ wi2, const float* __restrict__ wr2,
                         const float* __restrict__ wi3, const float* __restrict__ wr3,
                         float* __restrict__ ws) {
    int e = blockIdx.x * 256 + threadIdx.x;
    if (e < 28672) {            // L1: 7 chunks, M=128, K=200
        int c = e / 4096, r = e % 4096, m = r / 32, k = c * 32 + (r % 32);
        float v = 0.f;
        if (k < 200) v = (m < 64) ? wi1[m * 200 + k] : wr1[(m - 64) * 200 + k];
        ((unsigned short*)(ws + OFF_AB1))[e] = f2bf(v);
    } else if (e < 45056) {     // L2: 2 chunks, M=256, K=64
        int i = e - 28672;
        int c = i / 8192, r = i % 8192, m = r / 32, k = c * 32 + (r % 32);
        float v = (m < 128) ? wi2[m * 64 + k] : wr2[(m - 128) * 64 + k];
        ((unsigned short*)(ws + OFF_AB2))[i] = f2bf(v);
    } else if (e < 110592) {    // L3: 4 chunks, M=512, K=128
        int i = e - 45056;
        int c = i / 16384, r = i % 16384, m = r / 32, k = c * 32 + (r % 32);
        float v = (m < 256) ? wi3[m * 128 + k] : wr3[(m - 256) * 128 + k];
        ((unsigned short*)(ws + OFF_AB3))[i] = f2bf(v);
    } else if (e < 111488) {    // 896 BN stat accumulators
        ws[OFF_SUM1 + (e - 110592)] = 0.f;
    }
}

// ---------------- P1 layer 1 (MFMA): K=200(->224), M=128, 16x16, s=2 -------
// grid 2048 (2 blocks/image, n-halves of 128). 4 waves: mw=(w&1)*64, nw=(w>>1)*64.
__global__ __launch_bounds__(256) void p1m_l1(
    const float* __restrict__ x,            // [B][200][256]
    const unsigned short* __restrict__ ab,  // [7][128][32] bf16
    float* __restrict__ xi,                 // [B][64][256]
    float* __restrict__ rpre,               // [B][64][64]
    float* __restrict__ ssum, float* __restrict__ ssqs)
{
    __shared__ short As[128 * 40];
    __shared__ short Xs[128 * 40];
    const int tid = threadIdx.x, wave = tid >> 6, lane = tid & 63;
    const int l15 = lane & 15, qd = lane >> 4;
    const int b = blockIdx.x >> 1, nhalf = blockIdx.x & 1, n0 = nhalf * 128;
    const int mw = (wave & 1) * 64, nw = (wave >> 1) * 64;
    const float* xb = x + (size_t)b * 200 * 256 + n0;

    floatx4 acc[4][4];
    #pragma unroll
    for (int i = 0; i < 4; ++i)
        #pragma unroll
        for (int j = 0; j < 4; ++j) acc[i][j] = (floatx4){0.f, 0.f, 0.f, 0.f};

    for (int c = 0; c < 7; ++c) {
        // stage A chunk [128][32] bf16, linear 16B
        const uint4* ag = (const uint4*)(ab + (size_t)c * 128 * 32);
        #pragma unroll
        for (int e = tid; e < 512; e += 256)
            *(uint4*)(As + (e >> 2) * 40 + (e & 3) * 8) = ag[e];
        // stage X transposed+cvt: Xs[nl][k] bf16, k-pairs packed b32
        const int k0 = c * 32;
        for (int e = tid; e < 2048; e += 256) {
            int nl = e & 127, kp = e >> 7, k = k0 + 2 * kp;
            float v0 = 0.f, v1 = 0.f;
            if (k < 200) { v0 = xb[(size_t)k * 256 + nl]; v1 = xb[(size_t)(k + 1) * 256 + nl]; }
            *(unsigned*)(Xs + nl * 40 + kp * 2) = (unsigned)f2bf(v0) | ((unsigned)f2bf(v1) << 16);
        }
        __syncthreads();
        short8 af[4], bf[4];
        #pragma unroll
        for (int i = 0; i < 4; ++i)
            af[i] = *(const short8*)(As + (mw + i * 16 + l15) * 40 + qd * 8);
        #pragma unroll
        for (int j = 0; j < 4; ++j)
            bf[j] = *(const short8*)(Xs + (nw + j * 16 + l15) * 40 + qd * 8);
        #pragma unroll
        for (int i = 0; i < 4; ++i)
            #pragma unroll
            for (int j = 0; j < 4; ++j)
                acc[i][j] = __builtin_amdgcn_mfma_f32_16x16x32_bf16(af[i], bf[j], acc[i][j], 0, 0, 0);
        __syncthreads();
    }

    if (mw == 0) {  // xi rows m = mt*16 + qd*4 + r  (all < 64)
        #pragma unroll
        for (int mt = 0; mt < 4; ++mt)
            #pragma unroll
            for (int nt = 0; nt < 4; ++nt)
                #pragma unroll
                for (int r = 0; r < 4; ++r)
                    xi[((size_t)b * 64 + mt * 16 + qd * 4 + r) * 256 + n0 + nw + nt * 16 + l15] =
                        acc[mt][nt][r];
    } else {        // red rows -> 2x2 avgpool + BN stats
        const int h2b = 4 * nhalf + 2 * (wave >> 1);
        const bool vl = (lane & 1) == 0;
        #pragma unroll
        for (int mt = 0; mt < 4; ++mt) {
            #pragma unroll
            for (int r = 0; r < 4; ++r) {
                const int mr = mt * 16 + qd * 4 + r;
                float s1 = 0.f, s2 = 0.f;
                #pragma unroll
                for (int ntp = 0; ntp < 2; ++ntp) {
                    float sum = acc[mt][2 * ntp][r] + acc[mt][2 * ntp + 1][r]; // h-pair
                    float pool = 0.25f * (sum + __shfl_xor(sum, 1));           // w-pair
                    if (vl) {
                        rpre[((size_t)b * 64 + mr) * 64 + (h2b + ntp) * 8 + (l15 >> 1)] = pool;
                        s1 += pool; s2 += pool * pool;
                    }
                }
                #pragma unroll
                for (int off = 1; off < 16; off <<= 1) {
                    s1 += __shfl_xor(s1, off); s2 += __shfl_xor(s2, off);
                }
                if (l15 == 0) { atomicAdd(ssum + mr, s1); atomicAdd(ssqs + mr, s2); }
            }
        }
    }
}

// ---------------- P1 layer 2 (MFMA): K=64, M=256, 8x8, s=2 -----------------
// grid 1024. 4 waves: mw=wave*64, all n (64 pixels).
__global__ __launch_bounds__(256) void p1m_l2(
    const float* __restrict__ x,            // [B][64][64]
    const unsigned short* __restrict__ ab,  // [2][256][32] bf16
    float* __restrict__ xi,                 // [B][128][64]
    float* __restrict__ rpre,               // [B][128][16]
    float* __restrict__ ssum, float* __restrict__ ssqs)
{
    __shared__ short As[256 * 40];
    __shared__ short Xs[64 * 40];
    const int tid = threadIdx.x, wave = tid >> 6, lane = tid & 63;
    const int l15 = lane & 15, qd = lane >> 4;
    const int b = blockIdx.x, mw = wave * 64;
    const float* xb = x + (size_t)b * 64 * 64;

    floatx4 acc[4][4];
    #pragma unroll
    for (int i = 0; i < 4; ++i)
        #pragma unroll
        for (int j = 0; j < 4; ++j) acc[i][j] = (floatx4){0.f, 0.f, 0.f, 0.f};

    for (int c = 0; c < 2; ++c) {
        const uint4* ag = (const uint4*)(ab + (size_t)c * 256 * 32);
        #pragma unroll
        for (int e = tid; e < 1024; e += 256)
            *(uint4*)(As + (e >> 2) * 40 + (e & 3) * 8) = ag[e];
        const int k0 = c * 32;
        #pragma unroll
        for (int e = tid; e < 1024; e += 256) {
            int nl = e & 63, kp = e >> 6, k = k0 + 2 * kp;
            float v0 = xb[(size_t)k * 64 + nl], v1 = xb[(size_t)(k + 1) * 64 + nl];
            *(unsigned*)(Xs + nl * 40 + kp * 2) = (unsigned)f2bf(v0) | ((unsigned)f2bf(v1) << 16);
        }
        __syncthreads();
        short8 af[4], bf[4];
        #pragma unroll
        for (int i = 0; i < 4; ++i)
            af[i] = *(const short8*)(As + (mw + i * 16 + l15) * 40 + qd * 8);
        #pragma unroll
        for (int j = 0; j < 4; ++j)
            bf[j] = *(const short8*)(Xs + (j * 16 + l15) * 40 + qd * 8);
        #pragma unroll
        for (int i = 0; i < 4; ++i)
            #pragma unroll
            for (int j = 0; j < 4; ++j)
                acc[i][j] = __builtin_amdgcn_mfma_f32_16x16x32_bf16(af[i], bf[j], acc[i][j], 0, 0, 0);
        __syncthreads();
    }

    if (wave < 2) {  // xi rows m = wave*64 + mt*16 + qd*4 + r (<128)
        #pragma unroll
        for (int mt = 0; mt < 4; ++mt)
            #pragma unroll
            for (int nt = 0; nt < 4; ++nt)
                #pragma unroll
                for (int r = 0; r < 4; ++r)
                    xi[((size_t)b * 128 + mw + mt * 16 + qd * 4 + r) * 64 + nt * 16 + l15] =
                        acc[mt][nt][r];
    } else {         // red: 2x2 pool on 8x8 (n=nt*16+l15: h=2nt+(l15>>3), w=l15&7)
        const bool vl = (lane & 9) == 0;        // w even (bit0) and h even (bit3)
        const int w2 = (l15 & 7) >> 1;
        #pragma unroll
        for (int mt = 0; mt < 4; ++mt) {
            #pragma unroll
            for (int r = 0; r < 4; ++r) {
                const int mr = (wave - 2) * 64 + mt * 16 + qd * 4 + r;
                float s1 = 0.f, s2 = 0.f;
                #pragma unroll
                for (int nt = 0; nt < 4; ++nt) {
                    float v = acc[mt][nt][r];
                    float hp = v + __shfl_xor(v, 1);             // w-pair
                    float pool = 0.25f * (hp + __shfl_xor(hp, 8)); // h-pair
                    if (vl) {
                        rpre[((size_t)b * 128 + mr) * 16 + nt * 4 + w2] = pool;
                        s1 += pool; s2 += pool * pool;
                    }
                }
                #pragma unroll
                for (int off = 1; off < 16; off <<= 1) {
                    s1 += __shfl_xor(s1, off); s2 += __shfl_xor(s2, off);
                }
                if (l15 == 0) { atomicAdd(ssum + mr, s1); atomicAdd(ssqs + mr, s2); }
            }
        }
    }
}

// ---------------- P1 layer 3 (MFMA): K=128, M=512, 4x4, s=1 ----------------
// grid 1024. 4 waves: mw=wave*128, 8 m-tiles, single n-tile (16 pixels).
__global__ __launch_bounds__(256) void p1m_l3(
    const float* __restrict__ x,            // [B][128][16]
    const unsigned short* __restrict__ ab,  // [4][512][32] bf16
    float* __restrict__ xi,                 // [B][256][16]
    float* __restrict__ rpre,               // [B][256][16]
    float* __restrict__ ssum, float* __restrict__ ssqs)
{
    __shared__ short As[512 * 40];
    __shared__ short Xs[16 * 40];
    const int tid = threadIdx.x, wave = tid >> 6, lane = tid & 63;
    const int l15 = lane & 15, qd = lane >> 4;
    const int b = blockIdx.x, mw = wave * 128;
    const float* xb = x + (size_t)b * 128 * 16;

    floatx4 acc[8];
    #pragma unroll
    for (int i = 0; i < 8; ++i) acc[i] = (floatx4){0.f, 0.f, 0.f, 0.f};

    for (int c = 0; c < 4; ++c) {
        const uint4* ag = (const uint4*)(ab + (size_t)c * 512 * 32);
        #pragma unroll
        for (int e = tid; e < 2048; e += 256)
            *(uint4*)(As + (e >> 2) * 40 + (e & 3) * 8) = ag[e];
        const int k0 = c * 32;
        {
            int e = tid;   // 256 writes, one per thread
            int nl = e & 15, kp = e >> 4, k = k0 + 2 * kp;
            float v0 = xb[(size_t)k * 16 + nl], v1 = xb[(size_t)(k + 1) * 16 + nl];
            *(unsigned*)(Xs + nl * 40 + kp * 2) = (unsigned)f2bf(v0) | ((unsigned)f2bf(v1) << 16);
        }
        __syncthreads();
        short8 bfr = *(const short8*)(Xs + l15 * 40 + qd * 8);
        #pragma unroll
        for (int i = 0; i < 8; ++i) {
            short8 af = *(const short8*)(As + (mw + i * 16 + l15) * 40 + qd * 8);
            acc[i] = __builtin_amdgcn_mfma_f32_16x16x32_bf16(af, bfr, acc[i], 0, 0, 0);
        }
        __syncthreads();
    }

    if (wave < 2) {  // xi rows m = wave*128 + mt*16 + qd*4 + r (<256)
        #pragma unroll
        for (int mt = 0; mt < 8; ++mt)
            #pragma unroll
            for (int r = 0; r < 4; ++r)
                xi[((size_t)b * 256 + mw + mt * 16 + qd * 4 + r) * 16 + l15] = acc[mt][r];
    } else {         // red rows, no pool
        #pragma unroll
        for (int mt = 0; mt < 8; ++mt) {
            #pragma unroll
            for (int r = 0; r < 4; ++r) {
                const int mr = (wave - 2) * 128 + mt * 16 + qd * 4 + r;
                float v = acc[mt][r];
                rpre[((size_t)b * 256 + mr) * 16 + l15] = v;
                float s1 = v, s2 = v * v;
                #pragma unroll
                for (int off = 1; off < 16; off <<= 1) {
                    s1 += __shfl_xor(s1, off); s2 += __shfl_xor(s2, off);
                }
                if (l15 == 0) { atomicAdd(ssum + mr, s1); atomicAdd(ssqs + mr, s2); }
            }
        }
    }
}

// ---------------- P3 (unchanged) ----------------
template<int COUT, int H, int W, int K, int S, int PAD>
__global__ __launch_bounds__(256) void p3_kernel(
    const float* __restrict__ xi, const float* __restrict__ rpre,
    const float* __restrict__ ssum, const float* __restrict__ ssqs,
    const float* __restrict__ gamma, const float* __restrict__ beta,
    const float* __restrict__ wspan, float* __restrict__ out, float inv_cnt)
{
    constexpr int HO = (S == 2) ? H / 2 : H;
    constexpr int WO = (S == 2) ? W / 2 : W;
    constexpr int NQ = HO * WO;
    constexpr int K2 = K * K;
    constexpr int N  = H * W;
    static_assert((S == 2 && K == 2 && PAD == 0) || (S == 1 && K == 3 && PAD == 1), "");

    __shared__ float sc[COUT], sh[COUT];
    __shared__ float rl[COUT * NQ];
    __shared__ float kl[K2 * NQ];
    __shared__ float xil[(S == 1) ? COUT * N : 4];

    const int tid = threadIdx.x, b = blockIdx.x;

    for (int o = tid; o < COUT; o += 256) {
        float mean = ssum[o] * inv_cnt;
        float var  = ssqs[o] * inv_cnt - mean * mean;
        float s    = gamma[o] * rsqrtf(var + 1e-5f);
        sc[o] = s;
        sh[o] = beta[o] - mean * s;
    }
    __syncthreads();

    const float* rp = rpre + (size_t)b * COUT * NQ;
    for (int e = tid; e < COUT * NQ; e += 256) {
        int o = e / NQ;
        rl[e] = fmaxf(fmaf(sc[o], rp[e], sh[o]), 0.f);
    }
    const float* xb = xi + (size_t)b * COUT * N;
    if (S == 1) {
        for (int e = tid; e < COUT * N / 4; e += 256)
            ((float4*)xil)[e] = ((const float4*)xb)[e];
    }
    __syncthreads();

    for (int e = tid; e < K2 * NQ; e += 256) {
        int kk = e / NQ, q = e % NQ;
        float s = 0.f;
        for (int o = 0; o < COUT; ++o)
            s = fmaf(wspan[kk * COUT + o], rl[o * NQ + q], s);
        kl[e] = s;
    }
    __syncthreads();

    float* ob = out + (size_t)b * COUT * NQ;
    for (int e = tid; e < COUT * NQ; e += 256) {
        int o = e / NQ, q = e % NQ, ho = q / WO, wo = q % WO;
        float v;
        if (S == 2) {
            const float* p = xb + ((size_t)o * H + 2 * ho) * W + 2 * wo;
            float2 t  = *(const float2*)p;
            float2 bo = *(const float2*)(p + W);
            v = kl[0 * NQ + q] * t.x + kl[1 * NQ + q] * t.y
              + kl[2 * NQ + q] * bo.x + kl[3 * NQ + q] * bo.y;
        } else {
            v = 0.f;
            const float* xo = xil + o * N;
            #pragma unroll
            for (int ki = 0; ki < 3; ++ki) {
                int h = ho + ki - 1;
                if (h < 0 || h >= H) continue;
                #pragma unroll
                for (int kj = 0; kj < 3; ++kj) {
                    int w = wo + kj - 1;
                    if (w < 0 || w >= W) continue;
                    v = fmaf(kl[(ki * 3 + kj) * NQ + q], xo[h * W + w], v);
                }
            }
        }
        ob[e] = v;
    }
}

// ---------------- FC (unchanged) ----------------
__global__ __launch_bounds__(256) void fc_kernel(
    const float* __restrict__ h, const float* __restrict__ wfc,
    const float* __restrict__ bfc, float* __restrict__ out)
{
    __shared__ float hl[4096];
    __shared__ float red[4][16];
    const int tid = threadIdx.x, b = blockIdx.x;
    const float* hb = h + (size_t)b * 4096;
    for (int e = tid; e < 1024; e += 256)
        ((float4*)hl)[e] = ((const float4*)hb)[e];
    __syncthreads();
    float acc[16];
    #pragma unroll
    for (int n = 0; n < 16; ++n) acc[n] = 0.f;
    for (int i = 0; i < 16; ++i) {
        int f = tid + i * 256;
        float hv = hl[f];
        #pragma unroll
        for (int n = 0; n < 16; ++n)
            acc[n] = fmaf(hv, wfc[n * 4096 + f], acc[n]);
    }
    #pragma unroll
    for (int n = 0; n < 16; ++n) {
        float v = acc[n];
        #pragma unroll
        for (int off = 1; off < 64; off <<= 1) v += __shfl_xor(v, off);
        acc[n] = v;
    }
    const int wave = tid >> 6, lane = tid & 63;
    if (lane == 0) {
        #pragma unroll
        for (int n = 0; n < 16; ++n) red[wave][n] = acc[n];
    }
    __syncthreads();
    if (tid < 16)
        out[(size_t)b * 16 + tid] =
            red[0][tid] + red[1][tid] + red[2][tid] + red[3][tid] + bfc[tid];
}

// ---------------- launch ----------------
extern "C" void kernel_launch(void* const* d_in, const int* in_sizes, int n_in,
                              void* d_out, int out_size, void* d_ws, size_t ws_size,
                              hipStream_t stream) {
    const float* x    = (const float*)d_in[0];
    const float* Wi1  = (const float*)d_in[1];
    const float* Wr1  = (const float*)d_in[2];
    const float* g1   = (const float*)d_in[3];
    const float* be1  = (const float*)d_in[4];
    const float* Wsp1 = (const float*)d_in[5];
    const float* Wi2  = (const float*)d_in[6];
    const float* Wr2  = (const float*)d_in[7];
    const float* g2   = (const float*)d_in[8];
    const float* be2  = (const float*)d_in[9];
    const float* Wsp2 = (const float*)d_in[10];
    const float* Wi3  = (const float*)d_in[11];
    const float* Wr3  = (const float*)d_in[12];
    const float* g3   = (const float*)d_in[13];
    const float* be3  = (const float*)d_in[14];
    const float* Wsp3 = (const float*)d_in[15];
    const float* Wfc  = (const float*)d_in[16];
    const float* bfc  = (const float*)d_in[17];
    float* out = (float*)d_out;
    float* ws  = (float*)d_ws;

    const unsigned short* ab1 = (const unsigned short*)(ws + OFF_AB1);
    const unsigned short* ab2 = (const unsigned short*)(ws + OFF_AB2);
    const unsigned short* ab3 = (const unsigned short*)(ws + OFF_AB3);
    float* sum1 = ws + OFF_SUM1; float* sqs1 = ws + OFF_SQS1;
    float* sum2 = ws + OFF_SUM2; float* sqs2 = ws + OFF_SQS2;
    float* sum3 = ws + OFF_SUM3; float* sqs3 = ws + OFF_SQS3;
    float* xiA  = ws + OFF_XI;
    float* rB   = ws + OFF_RPRE;
    float* out1 = ws + OFF_OUT1;
    float* out2 = ws + OFF_OUT2;
    float* out3 = ws + OFF_OUT3;

    prep_all<<<436, 256, 0, stream>>>(Wi1, Wr1, Wi2, Wr2, Wi3, Wr3, ws);

    p1m_l1<<<2048, 256, 0, stream>>>(x, ab1, xiA, rB, sum1, sqs1);
    p3_kernel<64, 16, 16, 2, 2, 0><<<1024, 256, 0, stream>>>(
        xiA, rB, sum1, sqs1, g1, be1, Wsp1, out1, 1.f / 65536.f);

    p1m_l2<<<1024, 256, 0, stream>>>(out1, ab2, xiA, rB, sum2, sqs2);
    p3_kernel<128, 8, 8, 2, 2, 0><<<1024, 256, 0, stream>>>(
        xiA, rB, sum2, sqs2, g2, be2, Wsp2, out2, 1.f / 16384.f);

    p1m_l3<<<1024, 256, 0, stream>>>(out2, ab3, xiA, rB, sum3, sqs3);
    p3_kernel<256, 4, 4, 3, 1, 1><<<1024, 256, 0, stream>>>(
        xiA, rB, sum3, sqs3, g3, be3, Wsp3, out3, 1.f / 16384.f);

    fc_kernel<<<1024, 256, 0, stream>>>(out3, Wfc, bfc, out);
}